// Round 1
// baseline (11144.894 us; speedup 1.0000x reference)
//
#include <hip/hip_runtime.h>
#include <cstddef>
#include <cstdint>

typedef __bf16 bf16x8 __attribute__((ext_vector_type(8)));
typedef float  f32x4  __attribute__((ext_vector_type(4)));

#define AGENT __HIP_MEMORY_SCOPE_AGENT
#define RLX   __ATOMIC_RELAXED

static constexpr int B_ = 64, L_ = 512, E_ = 512, H_ = 1024;
static constexpr int NKX = E_ / 32;        // 16 k-tiles from x
static constexpr int NKH = H_ / 32;        // 32 k-tiles from h
static constexpr int NKK = NKX + NKH;      // 48
static constexpr size_t HS_ELEMS = (size_t)B_ * L_ * H_;  // 33554432

// workspace layout (bytes)
static constexpr size_t FLAGS_OFF = 0;                       // 256 uints (4 rg * 64)
static constexpr size_t MT_OFF    = 4096;                    // 512*64 f32 = 131072
static constexpr size_t HB_OFF    = MT_OFF + 131072;         // 2 * 65536 ushort = 262144
static constexpr size_t WP_OFF    = HB_OFF + 262144;         // 1536*4096 bf16 = 12582912
static constexpr size_t XF_OFF    = WP_OFF + 12582912;       // 64*512*512 bf16 = 33554432
static constexpr size_t WS_NEED   = XF_OFF + 33554432;       // ~44.4 MiB

__device__ inline unsigned short f2bf(float x) {
  unsigned u = __builtin_bit_cast(unsigned, x);
  u = u + 0x7FFFu + ((u >> 16) & 1u);
  return (unsigned short)(u >> 16);
}
__device__ inline bf16x8 ldfrag(const unsigned short* p) {
  uint4 v = *reinterpret_cast<const uint4*>(p);
  return __builtin_bit_cast(bf16x8, v);
}
__device__ inline f32x4 MFMA(bf16x8 a, bf16x8 b, f32x4 c) {
  return __builtin_amdgcn_mfma_f32_16x16x32_bf16(a, b, c, 0, 0, 0);
}
__device__ inline float sigm(float x)  { return 1.0f / (1.0f + __expf(-x)); }
__device__ inline float tanhf_(float x){ float e = __expf(2.0f * x); return 1.0f - 2.0f / (e + 1.0f); }

// ---------------- prep kernels ----------------

extern "C" __global__ void prep_mask(const float* __restrict__ mask, float* __restrict__ mT) {
  int idx = blockIdx.x * 256 + threadIdx.x;          // 32768 = 512*64
  int t = idx >> 6, b = idx & 63;
  mT[idx] = mask[(size_t)b * 512 + t];               // mT[t][b]
}

extern "C" __global__ void prep_h0flags(const float* __restrict__ h0,
                                        unsigned short* __restrict__ hb0,
                                        unsigned* __restrict__ flags) {
  int idx = blockIdx.x * 256 + threadIdx.x;          // 8192
  if (idx < 256) flags[idx] = 0u;
  int b = idx >> 7, U0 = (idx & 127) * 8;
  int kk = U0 >> 5, w = U0 & 31;
  unsigned short* dst = hb0 + kk * 2048 + b * 32 + w;
  const float* src = h0 + (size_t)b * 1024 + U0;
#pragma unroll
  for (int k = 0; k < 8; ++k) dst[k] = f2bf(src[k]);
}

extern "C" __global__ void prep_w(const float* __restrict__ Wf, const float* __restrict__ Wi,
                                  const float* __restrict__ Wo, const float* __restrict__ Wu,
                                  unsigned short* __restrict__ Wp) {
  // grid: x = kk(48), y = utile(16), z = gate(4)
  __shared__ unsigned short tile[32][72];
  int kk = blockIdx.x, ut = blockIdx.y, g = blockIdx.z;
  const float* W = (g == 0) ? Wf : (g == 1) ? Wi : (g == 2) ? Wo : Wu;
  int tid = threadIdx.x;
  int u0 = ut * 64;
#pragma unroll
  for (int i = 0; i < 8; ++i) {
    int idx = tid + i * 256;
    int dl = idx >> 6, ul = idx & 63;
    tile[dl][ul] = f2bf(W[(size_t)(kk * 32 + dl) * 1024 + u0 + ul]);
  }
  __syncthreads();
  int ql = tid >> 4, uu = (tid >> 2) & 3, p = tid & 3;
  int q = ut * 16 + ql;
  int l = (uu * 4 + g) + 16 * p;                     // lane in B-frag
  alignas(16) unsigned short v[8];
#pragma unroll
  for (int j = 0; j < 8; ++j) v[j] = tile[p * 8 + j][4 * ql + uu];
  *reinterpret_cast<uint4*>(Wp + ((size_t)(q * 48 + kk) * 64 + l) * 8) =
      *reinterpret_cast<uint4*>(v);
}

extern "C" __global__ void prep_x(const float* __restrict__ x, unsigned short* __restrict__ xf) {
  // blocks: 8192 -> t = bid>>4, kk = bid&15 ; threads: b = tid>>2, p = tid&3
  int bid = blockIdx.x, tid = threadIdx.x;
  int t = bid >> 4, kk = bid & 15;
  int b = tid >> 2, p = tid & 3;
  const float* src = x + ((size_t)b * 512 + t) * 512 + kk * 32 + p * 8;
  alignas(16) unsigned short v[8];
#pragma unroll
  for (int j = 0; j < 8; ++j) v[j] = f2bf(src[j]);
  *reinterpret_cast<uint4*>(xf + ((size_t)((t * 16 + kk) * 64 + b)) * 32 + p * 8) =
      *reinterpret_cast<uint4*>(v);
}

// ---------------- persistent recurrent kernel ----------------

extern "C" __global__ void __launch_bounds__(256, 1)
lstm_main(const unsigned short* __restrict__ Wp,
          const unsigned short* __restrict__ xf,
          unsigned short* __restrict__ hb,     // 2 * 65536 bf16 (ping-pong)
          const float* __restrict__ mT,
          const float* __restrict__ bf_, const float* __restrict__ bi_,
          const float* __restrict__ bo_, const float* __restrict__ bu_,
          const float* __restrict__ c0,
          float* __restrict__ out,
          unsigned* __restrict__ flags) {
  const int tid  = threadIdx.x;
  const int lane = tid & 63;
  const int wid  = tid >> 6;
  const int bid  = blockIdx.x;
  const int rg   = bid & 3;        // row group (16 batch rows)
  const int ug   = bid >> 2;       // unit group (16 hidden units)
  const int q    = ug * 4 + wid;   // unit quad owned by this wave
  const int b0   = rg * 16;
  const int col  = lane & 15;
  const int pr   = lane >> 4;      // 0..3
  const int g    = col & 3;        // gate: 0=f 1=i 2=o 3=chat
  const int U    = q * 4 + (col >> 2);   // global hidden unit of this lane

  // --- load weight fragments into registers (held for all 512 steps) ---
  bf16x8 w[NKK];
#pragma unroll
  for (int kk = 0; kk < NKK; ++kk)
    w[kk] = ldfrag(Wp + ((size_t)(q * NKK + kk) * 64 + lane) * 8);

  const float* bsrc = (g == 0) ? bf_ : (g == 1) ? bi_ : (g == 2) ? bo_ : bu_;
  const float bias = bsrc[U];

  float c[4];
#pragma unroll
  for (int r = 0; r < 4; ++r) c[r] = c0[(size_t)(b0 + pr * 4 + r) * H_ + U];

  // per-lane constant bases
  const unsigned short* xa = xf + (size_t)(b0 + col) * 32 + pr * 8;       // + t*32768 + kk*2048
  const int hbRdOffU = (b0 + col) * 16 + pr * 4;                          // uint index; + kk*1024
  const int hbWrOff  = (U >> 5) * 2048 + (b0 + pr * 4) * 32 + (U & 31);   // ushort; + r*32
  float* outH = out + (size_t)(b0 + pr * 4) * L_ * H_ + U;
  float* outC = outH + HS_ELEMS;
  const float* mTp = mT + b0 + pr * 4;

  for (int t = 0; t < L_; ++t) {
    f32x4 acc0 = {bias, bias, bias, bias};
    f32x4 acc1 = {0.f, 0.f, 0.f, 0.f};

    // ---- x-projection (no dependence on barrier) ----
    const unsigned short* xat = xa + (size_t)t * 32768;
#pragma unroll
    for (int kk = 0; kk < NKX; kk += 2) {
      acc0 = MFMA(ldfrag(xat + kk * 2048),       w[kk],     acc0);
      acc1 = MFMA(ldfrag(xat + (kk + 1) * 2048), w[kk + 1], acc1);
    }

    // ---- wait for step t-1 of this row group ----
    if (t > 0) {
      const unsigned tgt = (unsigned)t;
      int guard = 0;
      for (;;) {
        unsigned v = __hip_atomic_load(&flags[rg * 64 + lane], RLX, AGENT);
        if (__all(v >= tgt)) break;
        __builtin_amdgcn_s_sleep(1);
        if (++guard > (1 << 22)) break;   // safety: fail visibly, never hang
      }
    }

    // ---- h-projection (device-coherent reads, bypass stale L2) ----
    const unsigned* hbR =
        reinterpret_cast<const unsigned*>(hb + (size_t)(t & 1) * 65536) + hbRdOffU;
#pragma unroll
    for (int kk = 0; kk < NKH; kk += 2) {
      {
        const unsigned* p = hbR + kk * 1024;
        unsigned a0 = __hip_atomic_load(p + 0, RLX, AGENT);
        unsigned a1 = __hip_atomic_load(p + 1, RLX, AGENT);
        unsigned a2 = __hip_atomic_load(p + 2, RLX, AGENT);
        unsigned a3 = __hip_atomic_load(p + 3, RLX, AGENT);
        uint4 av; av.x = a0; av.y = a1; av.z = a2; av.w = a3;
        acc0 = MFMA(__builtin_bit_cast(bf16x8, av), w[NKX + kk], acc0);
      }
      {
        const unsigned* p = hbR + (kk + 1) * 1024;
        unsigned a0 = __hip_atomic_load(p + 0, RLX, AGENT);
        unsigned a1 = __hip_atomic_load(p + 1, RLX, AGENT);
        unsigned a2 = __hip_atomic_load(p + 2, RLX, AGENT);
        unsigned a3 = __hip_atomic_load(p + 3, RLX, AGENT);
        uint4 av; av.x = a0; av.y = a1; av.z = a2; av.w = a3;
        acc1 = MFMA(__builtin_bit_cast(bf16x8, av), w[NKX + kk + 1], acc1);
      }
    }
    f32x4 acc = acc0 + acc1;

    // ---- elementwise: quad (4 lanes) holds f,i,o,chat for one unit ----
    unsigned short* hbW = hb + (size_t)((t + 1) & 1) * 65536 + hbWrOff;
    const int base = lane & ~3;
    const float* mrow = mTp + (size_t)t * 64;
#pragma unroll
    for (int r = 0; r < 4; ++r) {
      float a  = acc[r];
      float gf = __shfl(a, base + 0, 64);
      float gi = __shfl(a, base + 1, 64);
      float go = __shfl(a, base + 2, 64);
      float gc = __shfl(a, base + 3, 64);
      float fv = sigm(gf), iv = sigm(gi), ov = sigm(go), cv = tanhf_(gc);
      float nc = fv * c[r] + iv * cv;
      float nh = ov * tanhf_(nc);
      float m  = mrow[r];
      nc *= m; nh *= m;
      c[r] = nc;
      if (g == 0) {
        __hip_atomic_store(hbW + r * 32, f2bf(nh), RLX, AGENT);   // h carry (bf16, LLC-coherent)
      } else if (g == 1) {
        outH[(size_t)t * H_ + (size_t)r * L_ * H_] = nh;          // hs output
      } else if (g == 2) {
        outC[(size_t)t * H_ + (size_t)r * L_ * H_] = nc;          // cs output
      }
    }

    // ---- signal: all our stores retired, then one flag store per block ----
    asm volatile("s_waitcnt vmcnt(0)" ::: "memory");
    __syncthreads();
    if (tid == 0)
      __hip_atomic_store(&flags[rg * 64 + ug], (unsigned)(t + 1), RLX, AGENT);
  }
}

// ---------------- host entry ----------------

extern "C" void kernel_launch(void* const* d_in, const int* in_sizes, int n_in,
                              void* d_out, int out_size, void* d_ws, size_t ws_size,
                              hipStream_t stream) {
  (void)in_sizes; (void)n_in; (void)out_size;
  const float* x    = (const float*)d_in[0];
  const float* mask = (const float*)d_in[1];
  const float* Wf_w = (const float*)d_in[2];
  const float* Wf_b = (const float*)d_in[3];
  const float* Wi_w = (const float*)d_in[4];
  const float* Wi_b = (const float*)d_in[5];
  const float* Wo_w = (const float*)d_in[6];
  const float* Wo_b = (const float*)d_in[7];
  const float* U_w  = (const float*)d_in[8];
  const float* U_b  = (const float*)d_in[9];
  const float* h0   = (const float*)d_in[10];
  const float* c0   = (const float*)d_in[11];
  float* out = (float*)d_out;
  char* ws = (char*)d_ws;
  if (ws_size < WS_NEED) return;   // fail visibly rather than corrupt memory

  unsigned*       flags = (unsigned*)(ws + FLAGS_OFF);
  float*          mT    = (float*)(ws + MT_OFF);
  unsigned short* hb    = (unsigned short*)(ws + HB_OFF);
  unsigned short* Wp    = (unsigned short*)(ws + WP_OFF);
  unsigned short* xfb   = (unsigned short*)(ws + XF_OFF);

  hipLaunchKernelGGL(prep_mask,    dim3(128),      dim3(256), 0, stream, mask, mT);
  hipLaunchKernelGGL(prep_h0flags, dim3(32),       dim3(256), 0, stream, h0, hb, flags);
  hipLaunchKernelGGL(prep_w,       dim3(48, 16, 4), dim3(256), 0, stream, Wf_w, Wi_w, Wo_w, U_w, Wp);
  hipLaunchKernelGGL(prep_x,       dim3(8192),     dim3(256), 0, stream, x, xfb);
  hipLaunchKernelGGL(lstm_main,    dim3(256),      dim3(256), 0, stream,
                     Wp, xfb, hb, mT, Wf_b, Wi_b, Wo_b, U_b, c0, out, flags);
}

// Round 3
// 4701.108 us; speedup vs baseline: 2.3707x; 2.3707x over previous
//
#include <hip/hip_runtime.h>
#include <cstddef>
#include <cstdint>

typedef __bf16 bf16x8 __attribute__((ext_vector_type(8)));
typedef float  f32x4  __attribute__((ext_vector_type(4)));
typedef unsigned u32x4v __attribute__((ext_vector_type(4)));

#define AGENT __HIP_MEMORY_SCOPE_AGENT
#define RLX   __ATOMIC_RELAXED

static constexpr int B_ = 64, L_ = 512, E_ = 512, H_ = 1024;
static constexpr int NKX = E_ / 32;        // 16 k-tiles from x
static constexpr int NKH = H_ / 32;        // 32 k-tiles from h
static constexpr int NKK = NKX + NKH;      // 48
static constexpr size_t HS_ELEMS = (size_t)B_ * L_ * H_;  // 33554432

// workspace layout (bytes)
static constexpr size_t FLAGS_OFF = 0;                       // 256 uints (4 rg * 64)
static constexpr size_t MT_OFF    = 4096;                    // 512*64 f32 = 131072
static constexpr size_t HB_OFF    = MT_OFF + 131072;         // 2 * 65536 ushort = 262144
static constexpr size_t WP_OFF    = HB_OFF + 262144;         // 1536*4096 bf16 = 12582912
static constexpr size_t XF_OFF    = WP_OFF + 12582912;       // 64*512*512 bf16 = 33554432
static constexpr size_t WS_NEED   = XF_OFF + 33554432;       // ~44.4 MiB

__device__ inline unsigned short f2bf(float x) {
  unsigned u = __builtin_bit_cast(unsigned, x);
  u = u + 0x7FFFu + ((u >> 16) & 1u);
  return (unsigned short)(u >> 16);
}
__device__ inline bf16x8 ldfrag(const unsigned short* p) {
  uint4 v = *reinterpret_cast<const uint4*>(p);
  return __builtin_bit_cast(bf16x8, v);
}
__device__ inline f32x4 MFMA(bf16x8 a, bf16x8 b, f32x4 c) {
  return __builtin_amdgcn_mfma_f32_16x16x32_bf16(a, b, c, 0, 0, 0);
}
__device__ inline float sigm(float x)  { return 1.0f / (1.0f + __expf(-x)); }
__device__ inline float tanhf_(float x){ float e = __expf(2.0f * x); return 1.0f - 2.0f / (e + 1.0f); }

// coherent (LLC, bypass L1/L2) 16B load — issue only, no wait
__device__ inline void coh_load16(u32x4v& d, const unsigned* p) {
  asm volatile("global_load_dwordx4 %0, %1, off sc0 sc1"
               : "=&v"(d) : "v"(p) : "memory");
}

// ---------------- prep kernels ----------------

extern "C" __global__ void prep_mask(const float* __restrict__ mask, float* __restrict__ mT) {
  int idx = blockIdx.x * 256 + threadIdx.x;          // 32768 = 512*64
  int t = idx >> 6, b = idx & 63;
  mT[idx] = mask[(size_t)b * 512 + t];               // mT[t][b]
}

extern "C" __global__ void prep_h0flags(const float* __restrict__ h0,
                                        unsigned short* __restrict__ hb0,
                                        unsigned* __restrict__ flags) {
  int idx = blockIdx.x * 256 + threadIdx.x;          // 8192
  if (idx < 256) flags[idx] = 0u;
  int b = idx >> 7, U0 = (idx & 127) * 8;
  int kk = U0 >> 5, w = U0 & 31;
  unsigned short* dst = hb0 + kk * 2048 + b * 32 + w;
  const float* src = h0 + (size_t)b * 1024 + U0;
#pragma unroll
  for (int k = 0; k < 8; ++k) dst[k] = f2bf(src[k]);
}

extern "C" __global__ void prep_w(const float* __restrict__ Wf, const float* __restrict__ Wi,
                                  const float* __restrict__ Wo, const float* __restrict__ Wu,
                                  unsigned short* __restrict__ Wp) {
  // grid: x = kk(48), y = utile(16), z = gate(4)
  __shared__ unsigned short tile[32][72];
  int kk = blockIdx.x, ut = blockIdx.y, g = blockIdx.z;
  const float* W = (g == 0) ? Wf : (g == 1) ? Wi : (g == 2) ? Wo : Wu;
  int tid = threadIdx.x;
  int u0 = ut * 64;
#pragma unroll
  for (int i = 0; i < 8; ++i) {
    int idx = tid + i * 256;
    int dl = idx >> 6, ul = idx & 63;
    tile[dl][ul] = f2bf(W[(size_t)(kk * 32 + dl) * 1024 + u0 + ul]);
  }
  __syncthreads();
  int ql = tid >> 4, uu = (tid >> 2) & 3, p = tid & 3;
  int q = ut * 16 + ql;
  int l = (uu * 4 + g) + 16 * p;                     // lane in B-frag
  alignas(16) unsigned short v[8];
#pragma unroll
  for (int j = 0; j < 8; ++j) v[j] = tile[p * 8 + j][4 * ql + uu];
  *reinterpret_cast<uint4*>(Wp + ((size_t)(q * 48 + kk) * 64 + l) * 8) =
      *reinterpret_cast<uint4*>(v);
}

extern "C" __global__ void prep_x(const float* __restrict__ x, unsigned short* __restrict__ xf) {
  // blocks: 8192 -> t = bid>>4, kk = bid&15 ; threads: b = tid>>2, p = tid&3
  int bid = blockIdx.x, tid = threadIdx.x;
  int t = bid >> 4, kk = bid & 15;
  int b = tid >> 2, p = tid & 3;
  const float* src = x + ((size_t)b * 512 + t) * 512 + kk * 32 + p * 8;
  alignas(16) unsigned short v[8];
#pragma unroll
  for (int j = 0; j < 8; ++j) v[j] = f2bf(src[j]);
  *reinterpret_cast<uint4*>(xf + ((size_t)((t * 16 + kk) * 64 + b)) * 32 + p * 8) =
      *reinterpret_cast<uint4*>(v);
}

// ---------------- persistent recurrent kernel ----------------

extern "C" __global__ void __launch_bounds__(256, 1)
lstm_main(const unsigned short* __restrict__ Wp,
          const unsigned short* __restrict__ xf,
          unsigned short* __restrict__ hb,     // 2 * 65536 bf16 (ping-pong)
          const float* __restrict__ mT,
          const float* __restrict__ bf_, const float* __restrict__ bi_,
          const float* __restrict__ bo_, const float* __restrict__ bu_,
          const float* __restrict__ c0,
          float* __restrict__ out,
          unsigned* __restrict__ flags) {
  const int tid  = threadIdx.x;
  const int lane = tid & 63;
  const int wid  = tid >> 6;
  const int bid  = blockIdx.x;
  const int rg   = bid & 3;        // row group (16 batch rows)
  const int ug   = bid >> 2;       // unit group (16 hidden units)
  const int q    = ug * 4 + wid;   // unit quad owned by this wave
  const int b0   = rg * 16;
  const int col  = lane & 15;
  const int pr   = lane >> 4;      // 0..3
  const int g    = col & 3;        // gate: 0=f 1=i 2=o 3=chat
  const int U    = q * 4 + (col >> 2);   // global hidden unit of this lane

  // compact h tile of this rg: [kk(32)][row(16)][32 bf16] = 32 KB
  __shared__ __align__(16) unsigned short hlds[16384];

  // --- load weight fragments into registers (held for all 512 steps) ---
  bf16x8 w[NKK];
#pragma unroll
  for (int kk = 0; kk < NKK; ++kk)
    w[kk] = ldfrag(Wp + ((size_t)(q * NKK + kk) * 64 + lane) * 8);

  const float* bsrc = (g == 0) ? bf_ : (g == 1) ? bi_ : (g == 2) ? bo_ : bu_;
  const float bias = bsrc[U];

  float c[4];
#pragma unroll
  for (int r = 0; r < 4; ++r) c[r] = c0[(size_t)(b0 + pr * 4 + r) * H_ + U];

  // per-lane constant bases
  const unsigned short* xa = xf + (size_t)(b0 + col) * 32 + pr * 8;   // + t*32768 + kk*2048
  const unsigned stageOff = (unsigned)(wid * 1024 + b0 * 16 + lane * 4);  // dword idx; + i*4096
  unsigned short* hldsW = &hlds[tid * 8];                             // + i*2048
  const unsigned short* hldsR = &hlds[col * 32 + pr * 8];             // + kk*512
  // h-store: this lane stores row r==g
  const int hbWrOff = (U >> 5) * 2048 + (b0 + pr * 4 + g) * 32 + (U & 31);
  float* outH = out + ((size_t)(b0 + pr * 4 + g) * L_) * H_ + U;      // + t*H
  float* outC = outH + HS_ELEMS;
  const float* mTp = mT + b0 + pr * 4;

  for (int t = 0; t < L_; ++t) {
    f32x4 acc0 = {bias, bias, bias, bias};
    f32x4 acc1 = {0.f, 0.f, 0.f, 0.f};

    // ---- x-projection (independent of barrier; fills poll wait) ----
    const unsigned short* xat = xa + (size_t)t * 32768;
#pragma unroll
    for (int kk = 0; kk < NKX; kk += 2) {
      acc0 = MFMA(ldfrag(xat + kk * 2048),       w[kk],     acc0);
      acc1 = MFMA(ldfrag(xat + (kk + 1) * 2048), w[kk + 1], acc1);
    }

    // ---- wait for step t-1 of this row group ----
    if (t > 0) {
      const unsigned tgt = (unsigned)t;
      int guard = 0;
      for (;;) {
        unsigned v = __hip_atomic_load(&flags[rg * 64 + lane], RLX, AGENT);
        if (__all((int)(v >= tgt))) break;
        if (++guard > (1 << 24)) break;   // safety: fail visibly, never hang
      }
    }

    // ---- cooperative coherent staging: h tile (32 KB) -> LDS, one round trip ----
    {
      const unsigned* src = reinterpret_cast<const unsigned*>(hb) +
                            (size_t)(t & 1) * 32768 + stageOff;
      u32x4v a0, a1, a2, a3, a4, a5, a6, a7;
      coh_load16(a0, src);
      coh_load16(a1, src + 1 * 4096);
      coh_load16(a2, src + 2 * 4096);
      coh_load16(a3, src + 3 * 4096);
      coh_load16(a4, src + 4 * 4096);
      coh_load16(a5, src + 5 * 4096);
      coh_load16(a6, src + 6 * 4096);
      coh_load16(a7, src + 7 * 4096);
      asm volatile("s_waitcnt vmcnt(0)" ::: "memory");
      __builtin_amdgcn_sched_barrier(0);
      *reinterpret_cast<u32x4v*>(hldsW + 0 * 2048) = a0;
      *reinterpret_cast<u32x4v*>(hldsW + 1 * 2048) = a1;
      *reinterpret_cast<u32x4v*>(hldsW + 2 * 2048) = a2;
      *reinterpret_cast<u32x4v*>(hldsW + 3 * 2048) = a3;
      *reinterpret_cast<u32x4v*>(hldsW + 4 * 2048) = a4;
      *reinterpret_cast<u32x4v*>(hldsW + 5 * 2048) = a5;
      *reinterpret_cast<u32x4v*>(hldsW + 6 * 2048) = a6;
      *reinterpret_cast<u32x4v*>(hldsW + 7 * 2048) = a7;
      __syncthreads();
    }

    // ---- h-projection from LDS ----
#pragma unroll
    for (int kk = 0; kk < NKH; kk += 2) {
      acc0 = MFMA(ldfrag(hldsR + kk * 512),       w[NKX + kk],     acc0);
      acc1 = MFMA(ldfrag(hldsR + (kk + 1) * 512), w[NKX + kk + 1], acc1);
    }
    f32x4 acc = acc0 + acc1;

    // ---- elementwise: quad (4 lanes) holds f,i,o,chat for one unit ----
    unsigned short* hbW = hb + (size_t)((t + 1) & 1) * 65536 + hbWrOff;
    const int base = lane & ~3;
    const float* mrow = mTp + (size_t)t * 64;
#pragma unroll
    for (int r = 0; r < 4; ++r) {
      float a  = acc[r];
      float gf = __shfl(a, base + 0, 64);
      float gi = __shfl(a, base + 1, 64);
      float go = __shfl(a, base + 2, 64);
      float gc = __shfl(a, base + 3, 64);
      float fv = sigm(gf), iv = sigm(gi), ov = sigm(go), cv = tanhf_(gc);
      float nc = fv * c[r] + iv * cv;
      float nh = ov * tanhf_(nc);
      float m  = mrow[r];
      nc *= m; nh *= m;
      c[r] = nc;
      if (r == g) {        // duty split: each quad lane stores its own row
        __hip_atomic_store(hbW, f2bf(nh), RLX, AGENT);   // h carry (bf16, LLC)
        outH[(size_t)t * H_] = nh;                       // hs output
        outC[(size_t)t * H_] = nc;                       // cs output
      }
    }

    // ---- signal: all stores retired, then one flag store per block ----
    asm volatile("s_waitcnt vmcnt(0)" ::: "memory");
    __syncthreads();
    if (tid == 0)
      __hip_atomic_store(&flags[rg * 64 + ug], (unsigned)(t + 1), RLX, AGENT);
  }
}

// ---------------- host entry ----------------

extern "C" void kernel_launch(void* const* d_in, const int* in_sizes, int n_in,
                              void* d_out, int out_size, void* d_ws, size_t ws_size,
                              hipStream_t stream) {
  (void)in_sizes; (void)n_in; (void)out_size;
  const float* x    = (const float*)d_in[0];
  const float* mask = (const float*)d_in[1];
  const float* Wf_w = (const float*)d_in[2];
  const float* Wf_b = (const float*)d_in[3];
  const float* Wi_w = (const float*)d_in[4];
  const float* Wi_b = (const float*)d_in[5];
  const float* Wo_w = (const float*)d_in[6];
  const float* Wo_b = (const float*)d_in[7];
  const float* U_w  = (const float*)d_in[8];
  const float* U_b  = (const float*)d_in[9];
  const float* h0   = (const float*)d_in[10];
  const float* c0   = (const float*)d_in[11];
  float* out = (float*)d_out;
  char* ws = (char*)d_ws;
  if (ws_size < WS_NEED) return;   // fail visibly rather than corrupt memory

  unsigned*       flags = (unsigned*)(ws + FLAGS_OFF);
  float*          mT    = (float*)(ws + MT_OFF);
  unsigned short* hb    = (unsigned short*)(ws + HB_OFF);
  unsigned short* Wp    = (unsigned short*)(ws + WP_OFF);
  unsigned short* xfb   = (unsigned short*)(ws + XF_OFF);

  hipLaunchKernelGGL(prep_mask,    dim3(128),      dim3(256), 0, stream, mask, mT);
  hipLaunchKernelGGL(prep_h0flags, dim3(32),       dim3(256), 0, stream, h0, hb, flags);
  hipLaunchKernelGGL(prep_w,       dim3(48, 16, 4), dim3(256), 0, stream, Wf_w, Wi_w, Wo_w, U_w, Wp);
  hipLaunchKernelGGL(prep_x,       dim3(8192),     dim3(256), 0, stream, x, xfb);
  hipLaunchKernelGGL(lstm_main,    dim3(256),      dim3(256), 0, stream,
                     Wp, xfb, hb, mT, Wf_b, Wi_b, Wo_b, U_b, c0, out, flags);
}